// Round 7
// baseline (278.172 us; speedup 1.0000x reference)
//
#include <hip/hip_runtime.h>
#include <cstdint>
#include <cstddef>

#define NP  1024
#define FD  10
#define BSZ 128
#define TPB 512   // 8 waves; each wave owns 128 rows (4 row-tiles of 32)
#define NW  8
#define RT  4     // row-tiles per wave

// One block per (pair, dir): bid = pair*2 + d.
//   d=0: rows = state(ag), cols = goal(dg)   (reward_s2g)
//   d=1: rows = goal(dg),  cols = state(ag)  (reward_g2s)
//
// R7 = R6 pass-1 MFMA core + R5-validated QUAD tracking + tiny 4-col GLOBAL
// rescan (validated recompute chain), no fp32 LDS plane.
// Rationale: R4-R6 shuffled ~45us of epilogue cost between pipes (TA-bound
// global 32-col gather -> tracker VALU -> LDS bank conflicts 28M). Quad
// tracking cuts rescan work 8x and the global 4-col rescan removes epilogue
// LDS entirely; LDS drops to 48KB -> 3 blocks/CU for cross-phase overlap.
// d(n,m) = cs_m - 2 r_n . c_m on the matrix pipe via bf16 split-3 limbs in
// K=32 (two chained 32x32x16 bf16 MFMAs). Term set IDENTICAL to R2-R6
// (absmax 0.0 x5): ChRh, CmRh, ClRh, ChRm, CmRm, ChRl, CmRl + cs split-3.
// LDS planes (48 KB):
//   P0 = [Ch|Cm]  -- MFMA1, BOTH k-halves (B supplies Rh then Rm)
//   P1 = [Cl|Ch]  -- MFMA2 k-half 0       (B supplies Rh then Rl)
//   P2 = [Cm|csh,csm,csl,0] -- MFMA2 k-half 1 (B supplies Rl then 1,1,1,0)
// Pass 1 tracks (min, ct) per REG-QUAD gi: quad covers contiguous abs cols
// ct*32 + 8*gi + 4*hh + {0..3} (C/D mapping m74/m101). Merge 8 disjoint
// candidates lexicographically (val, base) -> first-index tie semantics.
// Epilogue: 4-col fp32 rescan from GLOBAL (bit-identical staging-chain
// recompute, ascending j + strict < = reference first-index argmin), winner
// xy gather, threshold.
typedef __attribute__((ext_vector_type(8)))  __bf16 bf16x8;
typedef __attribute__((ext_vector_type(16))) float  f32x16;

__device__ inline unsigned int pk2(__bf16 a, __bf16 b) {
    union { __bf16 h; unsigned short u; } ua, ub;
    ua.h = a; ub.h = b;
    return (unsigned int)ua.u | ((unsigned int)ub.u << 16);
}

__device__ inline void split3(float x, __bf16& h, __bf16& m, __bf16& l) {
    h = (__bf16)x;
    float r1 = x - (float)h;    // exact (h carries x's exponent, 8-bit mantissa)
    m = (__bf16)r1;
    float r2 = r1 - (float)m;   // exact
    l = (__bf16)r2;
}

__device__ inline float min3f(float a, float b, float c) {
    return fminf(fminf(a, b), c);   // fuses to v_min3_f32; order-invariant exact
}

extern "C" __global__ __launch_bounds__(TPB, 6)   // 6 waves/EU = 3 blocks/CU; VGPR cap 85
void chamfer_pairs(const float* __restrict__ ag, const float* __restrict__ dg,
                   const float* __restrict__ nmean, const float* __restrict__ nstd,
                   float* __restrict__ out /* [BSZ], pre-zeroed */)
{
    __shared__ __align__(16) unsigned int ldsA[3 * NP * 4];  // 48 KB bf16 planes
    __shared__ float red[NW];

    const int bid  = blockIdx.x;        // 0..1023
    const int pair = bid >> 1;
    const int d    = bid & 1;
    const int tid  = threadIdx.x;
    const int wv   = tid >> 6;          // wave 0..7
    const int l    = tid & 63;
    const int ln   = l & 31;            // lane's row slot / col slot
    const int hh   = l >> 5;            // k-half owner

    const float* rowsrc = ((d == 0) ? ag : dg) + (size_t)pair * (NP * FD);
    const float* colsrc = ((d == 0) ? dg : ag) + (size_t)pair * (NP * FD);

    // -2*(std, mean) for vis features 5..8 (uniform -> scalar regs).
    const float s5 = -2.0f * nstd[5], m5 = -2.0f * nmean[5];
    const float s6 = -2.0f * nstd[6], m6 = -2.0f * nmean[6];
    const float s7 = -2.0f * nstd[7], m7 = -2.0f * nmean[7];
    const float s8 = -2.0f * nstd[8], m8 = -2.0f * nmean[8];
    const float std0 = nstd[0], mean0 = nmean[0];
    const float std1 = nstd[1], mean1 = nmean[1];

    // ---- Stage columns: C = t = fmaf(raw,-2s,-2m) (= -2c, proven chain),
    //      cs = 0.25*dot(t,t); split-3 into the 3 bf16 K-layout planes.
    for (int m = tid; m < NP; m += TPB) {
        const float* p = colsrc + (size_t)m * FD;
        float t0 = fmaf(p[5], s5, m5);
        float t1 = fmaf(p[6], s6, m6);
        float t2 = fmaf(p[7], s7, m7);
        float t3 = fmaf(p[8], s8, m8);
        float cs = 0.25f * (t0 * t0 + t1 * t1 + t2 * t2 + t3 * t3);
        __bf16 ch0, cm0, cl0, ch1, cm1, cl1, ch2, cm2, cl2, ch3, cm3, cl3;
        __bf16 qh, qm, ql;
        split3(t0, ch0, cm0, cl0);
        split3(t1, ch1, cm1, cl1);
        split3(t2, ch2, cm2, cl2);
        split3(t3, ch3, cm3, cl3);
        split3(cs, qh, qm, ql);
        const __bf16 z = (__bf16)0.0f;
        unsigned int chA = pk2(ch0, ch1), chB = pk2(ch2, ch3);
        unsigned int cmA = pk2(cm0, cm1), cmB = pk2(cm2, cm3);
        unsigned int clA = pk2(cl0, cl1), clB = pk2(cl2, cl3);
        uint4* pl = (uint4*)ldsA;
        pl[0 * NP + m] = make_uint4(chA, chB, cmA, cmB);            // P0 = [Ch|Cm]
        pl[1 * NP + m] = make_uint4(clA, clB, chA, chB);            // P1 = [Cl|Ch]
        pl[2 * NP + m] = make_uint4(cmA, cmB, pk2(qh, qm), pk2(ql, z)); // P2 = [Cm|cs3,0]
    }

    // ---- Rows: split-3 of r = -0.5*t (proven lineage); B fragments per
    //      k-half; threshold rthr = 6 - 0.25*dot(t,t).
    bf16x8 B1[RT], B2[RT];
    float  rthr[RT];
    const __bf16 kone = (__bf16)1.0f;
    const __bf16 kzb  = (__bf16)0.0f;
#pragma unroll
    for (int rt = 0; rt < RT; ++rt) {
        int n = wv * 128 + rt * 32 + ln;
        const float* p = rowsrc + (size_t)n * FD;
        float t0 = fmaf(p[5], s5, m5);
        float t1 = fmaf(p[6], s6, m6);
        float t2 = fmaf(p[7], s7, m7);
        float t3 = fmaf(p[8], s8, m8);
        float rss = 0.25f * (t0 * t0 + t1 * t1 + t2 * t2 + t3 * t3);
        rthr[rt] = 6.0f - rss;
        float r0 = -0.5f * t0, r1 = -0.5f * t1, r2 = -0.5f * t2, r3 = -0.5f * t3;
        __bf16 rh0, rm0, rl0, rh1, rm1, rl1, rh2, rm2, rl2, rh3, rm3, rl3;
        split3(r0, rh0, rm0, rl0);
        split3(r1, rh1, rm1, rl1);
        split3(r2, rh2, rm2, rl2);
        split3(r3, rh3, rm3, rl3);
        // MFMA1: K0-7 = Ch.Rh, Cm.Rh ; K8-15 = Ch.Rm, Cm.Rm  (A = P0 both halves)
        __bf16 p0 = hh ? rm0 : rh0;
        __bf16 p1 = hh ? rm1 : rh1;
        __bf16 p2 = hh ? rm2 : rh2;
        __bf16 p3 = hh ? rm3 : rh3;
        bf16x8 b1;
        b1[0] = p0; b1[1] = p1; b1[2] = p2; b1[3] = p3;
        b1[4] = p0; b1[5] = p1; b1[6] = p2; b1[7] = p3;
        // MFMA2: K0-7 = Cl.Rh, Ch.Rl (A=P1) ; K8-15 = Cm.Rl, cs*1 (A=P2)
        __bf16 q0 = hh ? rl0 : rh0;
        __bf16 q1 = hh ? rl1 : rh1;
        __bf16 q2 = hh ? rl2 : rh2;
        __bf16 q3 = hh ? rl3 : rh3;
        bf16x8 b2;
        b2[0] = q0; b2[1] = q1; b2[2] = q2; b2[3] = q3;
        b2[4] = hh ? kone : rl0;
        b2[5] = hh ? kone : rl1;
        b2[6] = hh ? kone : rl2;
        b2[7] = hh ? kzb  : rl3;
        B1[rt] = b1; B2[rt] = b2;
    }
    __syncthreads();

    // ---- Pass 1: 32 col-tiles; per ct: prefetch next a1/a2, 2 chained MFMAs
    //      x RT (two concurrent rt-chains), per-QUAD min4 + (min, ct) tracker
    //      (strict < keeps FIRST ct). 5 VALU/quad.
    f32x16 kz = {0.0f,0.0f,0.0f,0.0f,0.0f,0.0f,0.0f,0.0f,
                 0.0f,0.0f,0.0f,0.0f,0.0f,0.0f,0.0f,0.0f};
    float runmin[RT][4];
    int   runct[RT][4];
#pragma unroll
    for (int rt = 0; rt < RT; ++rt)
#pragma unroll
        for (int gi = 0; gi < 4; ++gi) { runmin[rt][gi] = 3.0e38f; runct[rt][gi] = 0; }

    const char* aBase1 = (const char*)ldsA + (size_t)ln * 16;                    // P0
    const char* aBase2 = (const char*)ldsA + (size_t)(1 + hh) * (NP * 16) + (size_t)ln * 16;

    bf16x8 a1 = *(const bf16x8*)(aBase1);
    bf16x8 a2 = *(const bf16x8*)(aBase2);
    for (int ct = 0; ct < 32; ++ct) {
        const int ctn = (ct + 1) & 31;                     // harmless wrap at 31
        bf16x8 a1n = *(const bf16x8*)(aBase1 + (size_t)ctn * 512);
        bf16x8 a2n = *(const bf16x8*)(aBase2 + (size_t)ctn * 512);
#pragma unroll
        for (int rt = 0; rt < RT; rt += 2) {
            f32x16 accA = __builtin_amdgcn_mfma_f32_32x32x16_bf16(a1, B1[rt],     kz, 0, 0, 0);
            f32x16 accB = __builtin_amdgcn_mfma_f32_32x32x16_bf16(a1, B1[rt + 1], kz, 0, 0, 0);
            accA = __builtin_amdgcn_mfma_f32_32x32x16_bf16(a2, B2[rt],     accA, 0, 0, 0);
            accB = __builtin_amdgcn_mfma_f32_32x32x16_bf16(a2, B2[rt + 1], accB, 0, 0, 0);
#pragma unroll
            for (int gi = 0; gi < 4; ++gi) {   // quad gi = abs cols ct*32+8*gi+4*hh+{0..3}
                float g = fminf(min3f(accA[4 * gi], accA[4 * gi + 1], accA[4 * gi + 2]),
                                accA[4 * gi + 3]);
                bool lt = g < runmin[rt][gi];      // strict < keeps FIRST ct
                runmin[rt][gi] = fminf(runmin[rt][gi], g);
                runct[rt][gi]  = lt ? ct : runct[rt][gi];
            }
#pragma unroll
            for (int gi = 0; gi < 4; ++gi) {
                float g = fminf(min3f(accB[4 * gi], accB[4 * gi + 1], accB[4 * gi + 2]),
                                accB[4 * gi + 3]);
                bool lt = g < runmin[rt + 1][gi];
                runmin[rt + 1][gi] = fminf(runmin[rt + 1][gi], g);
                runct[rt + 1][gi]  = lt ? ct : runct[rt + 1][gi];
            }
        }
        a1 = a1n; a2 = a2n;
    }

    // ---- Merge the 8 disjoint quad-candidates per row by lexicographic
    //      (val, abs base): contiguous disjoint ranges -> base order = column
    //      order -> reference first-index tie semantics. Then epilogue: lane
    //      handles its 2 assigned rows ((rt>>1)==hh): 4-col fp32 rescan from
    //      GLOBAL (bit-identical staging-chain recompute; ascending j +
    //      strict < = first-index argmin), winner xy, threshold.
    float sum = 0.0f;
#pragma unroll
    for (int rt = 0; rt < RT; ++rt) {
        float bv = runmin[rt][0];
        int   bc = runct[rt][0] * 32 + 4 * hh;
#pragma unroll
        for (int gi = 1; gi < 4; ++gi) {
            float v = runmin[rt][gi];
            int   c = runct[rt][gi] * 32 + 8 * gi + 4 * hh;
            bool take = (v < bv) || (v == bv && c < bc);
            bv = take ? v : bv;
            bc = take ? c : bc;
        }
        float ov = __shfl_xor(bv, 32);
        int   oc = __shfl_xor(bc, 32);
        bool take = (ov < bv) || (ov == bv && oc < bc);
        bv = take ? ov : bv;
        bc = take ? oc : bc;

        if ((rt >> 1) == hh) {               // hh=0 -> rt 0,1 ; hh=1 -> rt 2,3
            int n = wv * 128 + rt * 32 + ln;
            const float* pr = rowsrc + (size_t)n * FD;
            float t0 = fmaf(pr[5], s5, m5);
            float t1 = fmaf(pr[6], s6, m6);
            float t2 = fmaf(pr[7], s7, m7);
            float t3 = fmaf(pr[8], s8, m8);
            float vx = -0.5f * t0, vy = -0.5f * t1, vz = -0.5f * t2, vw = -0.5f * t3;
            float best = 3.0e38f;
            int   sel  = 0;
#pragma unroll
            for (int j = 0; j < 4; ++j) {
                const float* pc = colsrc + (size_t)(bc + j) * FD;
                float c0 = fmaf(pc[5], s5, m5);
                float c1 = fmaf(pc[6], s6, m6);
                float c2 = fmaf(pc[7], s7, m7);
                float c3 = fmaf(pc[8], s8, m8);
                float cs = 0.25f * (c0 * c0 + c1 * c1 + c2 * c2 + c3 * c3);
                float dd = fmaf(vx, c0, cs);
                dd = fmaf(vy, c1, dd);
                dd = fmaf(vz, c2, dd);
                dd = fmaf(vw, c3, dd);
                bool ltj = dd < best;        // ascending j + strict < = first idx
                best = fminf(best, dd);
                sel  = ltj ? j : sel;
            }
            int idx = bc + sel;
            const float* pw = colsrc + (size_t)idx * FD;
            float gx = fmaf(pw[0], std0, mean0);
            float gy = fmaf(pw[1], std1, mean1);
            float ax = fmaf(pr[0], std0, mean0);
            float ay = fmaf(pr[1], std1, mean1);
            float dx = ax - gx;
            float dy = ay - gy;
            float dist = sqrtf(dx * dx + dy * dy);
            if (best > rthr[rt]) dist = 1.0f;   // min_d > LATENT_DIST_THRESHOLD
            sum += dist;
        }
    }

    // ---- Reduce: wave shuffle, cross-wave LDS, one atomic per block.
    for (int o = 32; o > 0; o >>= 1) sum += __shfl_down(sum, o, 64);
    if ((tid & 63) == 0) red[tid >> 6] = sum;
    __syncthreads();
    if (tid == 0) {
        float s = red[0] + red[1] + red[2] + red[3]
                + red[4] + red[5] + red[6] + red[7];
        // out[b] = -(sum over 4 views x 2 dirs x 1024 rows) / 8192
        atomicAdd(&out[bid >> 3], s * (-1.0f / 8192.0f));
    }
}

extern "C" void kernel_launch(void* const* d_in, const int* in_sizes, int n_in,
                              void* d_out, int out_size, void* d_ws, size_t ws_size,
                              hipStream_t stream)
{
    const float* ag = (const float*)d_in[0];   // achieved_goal (128,4,1024,10)
    const float* dg = (const float*)d_in[1];   // desired_goal  (128,4,1024,10)
    const float* nm = (const float*)d_in[2];   // norm_mean (10,)
    const float* ns = (const float*)d_in[3];   // norm_std  (10,)

    hipMemsetAsync(d_out, 0, BSZ * sizeof(float), stream);   // out is accumulated
    chamfer_pairs<<<BSZ * 4 * 2, TPB, 0, stream>>>(ag, dg, nm, ns, (float*)d_out);
}

// Round 8
// 174.869 us; speedup vs baseline: 1.5907x; 1.5907x over previous
//
#include <hip/hip_runtime.h>
#include <cstdint>
#include <cstddef>

#define NP  1024
#define FD  10
#define BSZ 128
#define TPB 512   // 8 waves; each wave owns 128 rows (4 row-tiles of 32)
#define NW  8
#define RT  4     // row-tiles per wave

// One block per (pair, dir): bid = pair*2 + d.
//   d=0: rows = state(ag), cols = goal(dg)   (reward_s2g)
//   d=1: rows = goal(dg),  cols = state(ag)  (reward_g2s)
//
// R8 = R7 with the register bound reverted to (512,4). R7's (512,6) forced
// VGPR=40 -> tracker/fragment spills (WRITE 96MB, dur 221us). R7 proved the
// structure itself is right: SQ_LDS_BANK_CONFLICT = 0 with quad tracking +
// tiny global rescan. R5 compiled this tracker set at 64 VGPR under (512,4);
// with LDS 48.5KB and VGPR<=84 the runtime can still co-schedule 3 blocks/CU.
// d(n,m) = cs_m - 2 r_n . c_m on the matrix pipe via bf16 split-3 limbs in
// K=32 (two chained 32x32x16 bf16 MFMAs). Term set IDENTICAL to R2-R7
// (absmax 0.0 x6): ChRh, CmRh, ClRh, ChRm, CmRm, ChRl, CmRl + cs split-3.
// LDS planes (48 KB):
//   P0 = [Ch|Cm]  -- MFMA1, BOTH k-halves (B supplies Rh then Rm)
//   P1 = [Cl|Ch]  -- MFMA2 k-half 0       (B supplies Rh then Rl)
//   P2 = [Cm|csh,csm,csl,0] -- MFMA2 k-half 1 (B supplies Rl then 1,1,1,0)
// Pass 1 tracks (min, ct) per REG-QUAD gi: quad covers contiguous abs cols
// ct*32 + 8*gi + 4*hh + {0..3} (C/D mapping m74/m101). Merge 8 disjoint
// candidates lexicographically (val, base) -> first-index tie semantics.
// Epilogue: 4-col fp32 rescan from GLOBAL (bit-identical staging-chain
// recompute, ascending j + strict < = reference first-index argmin), winner
// xy gather, threshold.
typedef __attribute__((ext_vector_type(8)))  __bf16 bf16x8;
typedef __attribute__((ext_vector_type(16))) float  f32x16;

__device__ inline unsigned int pk2(__bf16 a, __bf16 b) {
    union { __bf16 h; unsigned short u; } ua, ub;
    ua.h = a; ub.h = b;
    return (unsigned int)ua.u | ((unsigned int)ub.u << 16);
}

__device__ inline void split3(float x, __bf16& h, __bf16& m, __bf16& l) {
    h = (__bf16)x;
    float r1 = x - (float)h;    // exact (h carries x's exponent, 8-bit mantissa)
    m = (__bf16)r1;
    float r2 = r1 - (float)m;   // exact
    l = (__bf16)r2;
}

__device__ inline float min3f(float a, float b, float c) {
    return fminf(fminf(a, b), c);   // fuses to v_min3_f32; order-invariant exact
}

extern "C" __global__ __launch_bounds__(TPB, 4)   // VGPR cap 128; no forced spills
void chamfer_pairs(const float* __restrict__ ag, const float* __restrict__ dg,
                   const float* __restrict__ nmean, const float* __restrict__ nstd,
                   float* __restrict__ out /* [BSZ], pre-zeroed */)
{
    __shared__ __align__(16) unsigned int ldsA[3 * NP * 4];  // 48 KB bf16 planes
    __shared__ float red[NW];

    const int bid  = blockIdx.x;        // 0..1023
    const int pair = bid >> 1;
    const int d    = bid & 1;
    const int tid  = threadIdx.x;
    const int wv   = tid >> 6;          // wave 0..7
    const int l    = tid & 63;
    const int ln   = l & 31;            // lane's row slot / col slot
    const int hh   = l >> 5;            // k-half owner

    const float* rowsrc = ((d == 0) ? ag : dg) + (size_t)pair * (NP * FD);
    const float* colsrc = ((d == 0) ? dg : ag) + (size_t)pair * (NP * FD);

    // -2*(std, mean) for vis features 5..8 (uniform -> scalar regs).
    const float s5 = -2.0f * nstd[5], m5 = -2.0f * nmean[5];
    const float s6 = -2.0f * nstd[6], m6 = -2.0f * nmean[6];
    const float s7 = -2.0f * nstd[7], m7 = -2.0f * nmean[7];
    const float s8 = -2.0f * nstd[8], m8 = -2.0f * nmean[8];
    const float std0 = nstd[0], mean0 = nmean[0];
    const float std1 = nstd[1], mean1 = nmean[1];

    // ---- Stage columns: C = t = fmaf(raw,-2s,-2m) (= -2c, proven chain),
    //      cs = 0.25*dot(t,t); split-3 into the 3 bf16 K-layout planes.
    for (int m = tid; m < NP; m += TPB) {
        const float* p = colsrc + (size_t)m * FD;
        float t0 = fmaf(p[5], s5, m5);
        float t1 = fmaf(p[6], s6, m6);
        float t2 = fmaf(p[7], s7, m7);
        float t3 = fmaf(p[8], s8, m8);
        float cs = 0.25f * (t0 * t0 + t1 * t1 + t2 * t2 + t3 * t3);
        __bf16 ch0, cm0, cl0, ch1, cm1, cl1, ch2, cm2, cl2, ch3, cm3, cl3;
        __bf16 qh, qm, ql;
        split3(t0, ch0, cm0, cl0);
        split3(t1, ch1, cm1, cl1);
        split3(t2, ch2, cm2, cl2);
        split3(t3, ch3, cm3, cl3);
        split3(cs, qh, qm, ql);
        const __bf16 z = (__bf16)0.0f;
        unsigned int chA = pk2(ch0, ch1), chB = pk2(ch2, ch3);
        unsigned int cmA = pk2(cm0, cm1), cmB = pk2(cm2, cm3);
        unsigned int clA = pk2(cl0, cl1), clB = pk2(cl2, cl3);
        uint4* pl = (uint4*)ldsA;
        pl[0 * NP + m] = make_uint4(chA, chB, cmA, cmB);            // P0 = [Ch|Cm]
        pl[1 * NP + m] = make_uint4(clA, clB, chA, chB);            // P1 = [Cl|Ch]
        pl[2 * NP + m] = make_uint4(cmA, cmB, pk2(qh, qm), pk2(ql, z)); // P2 = [Cm|cs3,0]
    }

    // ---- Rows: split-3 of r = -0.5*t (proven lineage); B fragments per
    //      k-half; threshold rthr = 6 - 0.25*dot(t,t).
    bf16x8 B1[RT], B2[RT];
    float  rthr[RT];
    const __bf16 kone = (__bf16)1.0f;
    const __bf16 kzb  = (__bf16)0.0f;
#pragma unroll
    for (int rt = 0; rt < RT; ++rt) {
        int n = wv * 128 + rt * 32 + ln;
        const float* p = rowsrc + (size_t)n * FD;
        float t0 = fmaf(p[5], s5, m5);
        float t1 = fmaf(p[6], s6, m6);
        float t2 = fmaf(p[7], s7, m7);
        float t3 = fmaf(p[8], s8, m8);
        float rss = 0.25f * (t0 * t0 + t1 * t1 + t2 * t2 + t3 * t3);
        rthr[rt] = 6.0f - rss;
        float r0 = -0.5f * t0, r1 = -0.5f * t1, r2 = -0.5f * t2, r3 = -0.5f * t3;
        __bf16 rh0, rm0, rl0, rh1, rm1, rl1, rh2, rm2, rl2, rh3, rm3, rl3;
        split3(r0, rh0, rm0, rl0);
        split3(r1, rh1, rm1, rl1);
        split3(r2, rh2, rm2, rl2);
        split3(r3, rh3, rm3, rl3);
        // MFMA1: K0-7 = Ch.Rh, Cm.Rh ; K8-15 = Ch.Rm, Cm.Rm  (A = P0 both halves)
        __bf16 p0 = hh ? rm0 : rh0;
        __bf16 p1 = hh ? rm1 : rh1;
        __bf16 p2 = hh ? rm2 : rh2;
        __bf16 p3 = hh ? rm3 : rh3;
        bf16x8 b1;
        b1[0] = p0; b1[1] = p1; b1[2] = p2; b1[3] = p3;
        b1[4] = p0; b1[5] = p1; b1[6] = p2; b1[7] = p3;
        // MFMA2: K0-7 = Cl.Rh, Ch.Rl (A=P1) ; K8-15 = Cm.Rl, cs*1 (A=P2)
        __bf16 q0 = hh ? rl0 : rh0;
        __bf16 q1 = hh ? rl1 : rh1;
        __bf16 q2 = hh ? rl2 : rh2;
        __bf16 q3 = hh ? rl3 : rh3;
        bf16x8 b2;
        b2[0] = q0; b2[1] = q1; b2[2] = q2; b2[3] = q3;
        b2[4] = hh ? kone : rl0;
        b2[5] = hh ? kone : rl1;
        b2[6] = hh ? kone : rl2;
        b2[7] = hh ? kzb  : rl3;
        B1[rt] = b1; B2[rt] = b2;
    }
    __syncthreads();

    // ---- Pass 1: 32 col-tiles; per ct: prefetch next a1/a2, 2 chained MFMAs
    //      x RT (two concurrent rt-chains), per-QUAD min4 + (min, ct) tracker
    //      (strict < keeps FIRST ct). 5 VALU/quad.
    f32x16 kz = {0.0f,0.0f,0.0f,0.0f,0.0f,0.0f,0.0f,0.0f,
                 0.0f,0.0f,0.0f,0.0f,0.0f,0.0f,0.0f,0.0f};
    float runmin[RT][4];
    int   runct[RT][4];
#pragma unroll
    for (int rt = 0; rt < RT; ++rt)
#pragma unroll
        for (int gi = 0; gi < 4; ++gi) { runmin[rt][gi] = 3.0e38f; runct[rt][gi] = 0; }

    const char* aBase1 = (const char*)ldsA + (size_t)ln * 16;                    // P0
    const char* aBase2 = (const char*)ldsA + (size_t)(1 + hh) * (NP * 16) + (size_t)ln * 16;

    bf16x8 a1 = *(const bf16x8*)(aBase1);
    bf16x8 a2 = *(const bf16x8*)(aBase2);
    for (int ct = 0; ct < 32; ++ct) {
        const int ctn = (ct + 1) & 31;                     // harmless wrap at 31
        bf16x8 a1n = *(const bf16x8*)(aBase1 + (size_t)ctn * 512);
        bf16x8 a2n = *(const bf16x8*)(aBase2 + (size_t)ctn * 512);
#pragma unroll
        for (int rt = 0; rt < RT; rt += 2) {
            f32x16 accA = __builtin_amdgcn_mfma_f32_32x32x16_bf16(a1, B1[rt],     kz, 0, 0, 0);
            f32x16 accB = __builtin_amdgcn_mfma_f32_32x32x16_bf16(a1, B1[rt + 1], kz, 0, 0, 0);
            accA = __builtin_amdgcn_mfma_f32_32x32x16_bf16(a2, B2[rt],     accA, 0, 0, 0);
            accB = __builtin_amdgcn_mfma_f32_32x32x16_bf16(a2, B2[rt + 1], accB, 0, 0, 0);
#pragma unroll
            for (int gi = 0; gi < 4; ++gi) {   // quad gi = abs cols ct*32+8*gi+4*hh+{0..3}
                float g = fminf(min3f(accA[4 * gi], accA[4 * gi + 1], accA[4 * gi + 2]),
                                accA[4 * gi + 3]);
                bool lt = g < runmin[rt][gi];      // strict < keeps FIRST ct
                runmin[rt][gi] = fminf(runmin[rt][gi], g);
                runct[rt][gi]  = lt ? ct : runct[rt][gi];
            }
#pragma unroll
            for (int gi = 0; gi < 4; ++gi) {
                float g = fminf(min3f(accB[4 * gi], accB[4 * gi + 1], accB[4 * gi + 2]),
                                accB[4 * gi + 3]);
                bool lt = g < runmin[rt + 1][gi];
                runmin[rt + 1][gi] = fminf(runmin[rt + 1][gi], g);
                runct[rt + 1][gi]  = lt ? ct : runct[rt + 1][gi];
            }
        }
        a1 = a1n; a2 = a2n;
    }

    // ---- Merge the 8 disjoint quad-candidates per row by lexicographic
    //      (val, abs base): contiguous disjoint ranges -> base order = column
    //      order -> reference first-index tie semantics. Then epilogue: lane
    //      handles its 2 assigned rows ((rt>>1)==hh): 4-col fp32 rescan from
    //      GLOBAL (bit-identical staging-chain recompute; ascending j +
    //      strict < = first-index argmin), winner xy, threshold.
    float sum = 0.0f;
#pragma unroll
    for (int rt = 0; rt < RT; ++rt) {
        float bv = runmin[rt][0];
        int   bc = runct[rt][0] * 32 + 4 * hh;
#pragma unroll
        for (int gi = 1; gi < 4; ++gi) {
            float v = runmin[rt][gi];
            int   c = runct[rt][gi] * 32 + 8 * gi + 4 * hh;
            bool take = (v < bv) || (v == bv && c < bc);
            bv = take ? v : bv;
            bc = take ? c : bc;
        }
        float ov = __shfl_xor(bv, 32);
        int   oc = __shfl_xor(bc, 32);
        bool take = (ov < bv) || (ov == bv && oc < bc);
        bv = take ? ov : bv;
        bc = take ? oc : bc;

        if ((rt >> 1) == hh) {               // hh=0 -> rt 0,1 ; hh=1 -> rt 2,3
            int n = wv * 128 + rt * 32 + ln;
            const float* pr = rowsrc + (size_t)n * FD;
            float t0 = fmaf(pr[5], s5, m5);
            float t1 = fmaf(pr[6], s6, m6);
            float t2 = fmaf(pr[7], s7, m7);
            float t3 = fmaf(pr[8], s8, m8);
            float vx = -0.5f * t0, vy = -0.5f * t1, vz = -0.5f * t2, vw = -0.5f * t3;
            float best = 3.0e38f;
            int   sel  = 0;
#pragma unroll
            for (int j = 0; j < 4; ++j) {
                const float* pc = colsrc + (size_t)(bc + j) * FD;
                float c0 = fmaf(pc[5], s5, m5);
                float c1 = fmaf(pc[6], s6, m6);
                float c2 = fmaf(pc[7], s7, m7);
                float c3 = fmaf(pc[8], s8, m8);
                float cs = 0.25f * (c0 * c0 + c1 * c1 + c2 * c2 + c3 * c3);
                float dd = fmaf(vx, c0, cs);
                dd = fmaf(vy, c1, dd);
                dd = fmaf(vz, c2, dd);
                dd = fmaf(vw, c3, dd);
                bool ltj = dd < best;        // ascending j + strict < = first idx
                best = fminf(best, dd);
                sel  = ltj ? j : sel;
            }
            int idx = bc + sel;
            const float* pw = colsrc + (size_t)idx * FD;
            float gx = fmaf(pw[0], std0, mean0);
            float gy = fmaf(pw[1], std1, mean1);
            float ax = fmaf(pr[0], std0, mean0);
            float ay = fmaf(pr[1], std1, mean1);
            float dx = ax - gx;
            float dy = ay - gy;
            float dist = sqrtf(dx * dx + dy * dy);
            if (best > rthr[rt]) dist = 1.0f;   // min_d > LATENT_DIST_THRESHOLD
            sum += dist;
        }
    }

    // ---- Reduce: wave shuffle, cross-wave LDS, one atomic per block.
    for (int o = 32; o > 0; o >>= 1) sum += __shfl_down(sum, o, 64);
    if ((tid & 63) == 0) red[tid >> 6] = sum;
    __syncthreads();
    if (tid == 0) {
        float s = red[0] + red[1] + red[2] + red[3]
                + red[4] + red[5] + red[6] + red[7];
        // out[b] = -(sum over 4 views x 2 dirs x 1024 rows) / 8192
        atomicAdd(&out[bid >> 3], s * (-1.0f / 8192.0f));
    }
}

extern "C" void kernel_launch(void* const* d_in, const int* in_sizes, int n_in,
                              void* d_out, int out_size, void* d_ws, size_t ws_size,
                              hipStream_t stream)
{
    const float* ag = (const float*)d_in[0];   // achieved_goal (128,4,1024,10)
    const float* dg = (const float*)d_in[1];   // desired_goal  (128,4,1024,10)
    const float* nm = (const float*)d_in[2];   // norm_mean (10,)
    const float* ns = (const float*)d_in[3];   // norm_std  (10,)

    hipMemsetAsync(d_out, 0, BSZ * sizeof(float), stream);   // out is accumulated
    chamfer_pairs<<<BSZ * 4 * 2, TPB, 0, stream>>>(ag, dg, nm, ns, (float*)d_out);
}

// Round 9
// 170.147 us; speedup vs baseline: 1.6349x; 1.0278x over previous
//
#include <hip/hip_runtime.h>
#include <cstdint>
#include <cstddef>

#define NP  1024
#define FD  10
#define BSZ 128
#define TPB 512   // 8 waves; each wave owns 128 rows (4 row-tiles of 32)
#define NW  8
#define RT  4     // row-tiles per wave

// One block per (pair, dir): bid = pair*2 + d.
//   d=0: rows = state(ag), cols = goal(dg)   (reward_s2g)
//   d=1: rows = goal(dg),  cols = state(ag)  (reward_g2s)
//
// R9 = R8 with de-duplicated LDS half-planes for 4-blocks/CU residency.
// R4-R8 plateaued at ~107-110us across four different epilogues; occupancy
// 37% (LDS 48.5KB -> 3 blocks/CU vs grid 4/CU -> two-round (3,1) schedule
// with tails). Fix: P0/P1/P2 stored Ch,Cm twice; store four 8-byte
// half-planes {Ch, Cm, Cl, cs} (32KB) and build each A-fragment from two
// ds_read_b64 (bit-identical bytes -> identical numerics, absmax 0.0 x7).
// 32.9KB -> 4 blocks/CU co-resident (VGPR<=64, as R8 compiled) -> one flat
// round, 32 waves/CU.
// d(n,m) = cs_m - 2 r_n . c_m via bf16 split-3 limbs in K=32 (two chained
// 32x32x16 bf16 MFMAs). Terms: ChRh, CmRh, ClRh, ChRm, CmRm, ChRl, CmRl +
// cs split-3 (drops only ClRm/ClRl <= 2^-24 rel).
// A-fragments per k-half (hh = lane>>5):
//   a1 = [Ch | Cm]            (B supplies Rh k-half0, Rm k-half1)
//   a2 = hh ? [Cm | cs] : [Cl | Ch]   (B: h0 (Rh,Rl), h1 (Rl, 1,1,1,0))
// Pass 1 tracks (min, ct) per REG-QUAD gi: quad covers contiguous abs cols
// ct*32 + 8*gi + 4*hh + {0..3} (C/D mapping m74/m101). Merge 8 disjoint
// candidates lexicographically (val, base) -> first-index tie semantics.
// Epilogue: 4-col fp32 rescan from GLOBAL (bit-identical staging-chain
// recompute, ascending j + strict < = reference first-index argmin), winner
// xy gather, threshold. Proven zero-conflict, zero-spill in R8.
typedef __attribute__((ext_vector_type(8)))  __bf16 bf16x8;
typedef __attribute__((ext_vector_type(16))) float  f32x16;

__device__ inline unsigned int pk2(__bf16 a, __bf16 b) {
    union { __bf16 h; unsigned short u; } ua, ub;
    ua.h = a; ub.h = b;
    return (unsigned int)ua.u | ((unsigned int)ub.u << 16);
}

__device__ inline void split3(float x, __bf16& h, __bf16& m, __bf16& l) {
    h = (__bf16)x;
    float r1 = x - (float)h;    // exact (h carries x's exponent, 8-bit mantissa)
    m = (__bf16)r1;
    float r2 = r1 - (float)m;   // exact
    l = (__bf16)r2;
}

__device__ inline float min3f(float a, float b, float c) {
    return fminf(fminf(a, b), c);   // fuses to v_min3_f32; order-invariant exact
}

extern "C" __global__ __launch_bounds__(TPB, 4)   // VGPR cap 128 (R8-proven codegen)
void chamfer_pairs(const float* __restrict__ ag, const float* __restrict__ dg,
                   const float* __restrict__ nmean, const float* __restrict__ nstd,
                   float* __restrict__ out /* [BSZ], pre-zeroed */)
{
    // Four 8-byte half-planes: Ch, Cm, Cl, cs -> 4 x 8KB = 32 KB.
    __shared__ __align__(16) unsigned int ldsH[4 * NP * 2];
    __shared__ float red[NW];

    const int bid  = blockIdx.x;        // 0..1023
    const int pair = bid >> 1;
    const int d    = bid & 1;
    const int tid  = threadIdx.x;
    const int wv   = tid >> 6;          // wave 0..7
    const int l    = tid & 63;
    const int ln   = l & 31;            // lane's row slot / col slot
    const int hh   = l >> 5;            // k-half owner

    const float* rowsrc = ((d == 0) ? ag : dg) + (size_t)pair * (NP * FD);
    const float* colsrc = ((d == 0) ? dg : ag) + (size_t)pair * (NP * FD);

    // -2*(std, mean) for vis features 5..8 (uniform -> scalar regs).
    const float s5 = -2.0f * nstd[5], m5 = -2.0f * nmean[5];
    const float s6 = -2.0f * nstd[6], m6 = -2.0f * nmean[6];
    const float s7 = -2.0f * nstd[7], m7 = -2.0f * nmean[7];
    const float s8 = -2.0f * nstd[8], m8 = -2.0f * nmean[8];
    const float std0 = nstd[0], mean0 = nmean[0];
    const float std1 = nstd[1], mean1 = nmean[1];

    // ---- Stage columns: C = t = fmaf(raw,-2s,-2m) (= -2c, proven chain),
    //      cs = 0.25*dot(t,t); split-3 into the 4 half-planes (same bytes as
    //      R8's P0/P1/P2, de-duplicated).
    for (int m = tid; m < NP; m += TPB) {
        const float* p = colsrc + (size_t)m * FD;
        float t0 = fmaf(p[5], s5, m5);
        float t1 = fmaf(p[6], s6, m6);
        float t2 = fmaf(p[7], s7, m7);
        float t3 = fmaf(p[8], s8, m8);
        float cs = 0.25f * (t0 * t0 + t1 * t1 + t2 * t2 + t3 * t3);
        __bf16 ch0, cm0, cl0, ch1, cm1, cl1, ch2, cm2, cl2, ch3, cm3, cl3;
        __bf16 qh, qm, ql;
        split3(t0, ch0, cm0, cl0);
        split3(t1, ch1, cm1, cl1);
        split3(t2, ch2, cm2, cl2);
        split3(t3, ch3, cm3, cl3);
        split3(cs, qh, qm, ql);
        const __bf16 z = (__bf16)0.0f;
        uint2* ph = (uint2*)ldsH;
        ph[0 * NP + m] = make_uint2(pk2(ch0, ch1), pk2(ch2, ch3));   // Ch
        ph[1 * NP + m] = make_uint2(pk2(cm0, cm1), pk2(cm2, cm3));   // Cm
        ph[2 * NP + m] = make_uint2(pk2(cl0, cl1), pk2(cl2, cl3));   // Cl
        ph[3 * NP + m] = make_uint2(pk2(qh, qm),   pk2(ql, z));      // cs3
    }

    // ---- Rows: split-3 of r = -0.5*t (proven lineage); B fragments per
    //      k-half; threshold rthr = 6 - 0.25*dot(t,t).
    bf16x8 B1[RT], B2[RT];
    float  rthr[RT];
    const __bf16 kone = (__bf16)1.0f;
    const __bf16 kzb  = (__bf16)0.0f;
#pragma unroll
    for (int rt = 0; rt < RT; ++rt) {
        int n = wv * 128 + rt * 32 + ln;
        const float* p = rowsrc + (size_t)n * FD;
        float t0 = fmaf(p[5], s5, m5);
        float t1 = fmaf(p[6], s6, m6);
        float t2 = fmaf(p[7], s7, m7);
        float t3 = fmaf(p[8], s8, m8);
        float rss = 0.25f * (t0 * t0 + t1 * t1 + t2 * t2 + t3 * t3);
        rthr[rt] = 6.0f - rss;
        float r0 = -0.5f * t0, r1 = -0.5f * t1, r2 = -0.5f * t2, r3 = -0.5f * t3;
        __bf16 rh0, rm0, rl0, rh1, rm1, rl1, rh2, rm2, rl2, rh3, rm3, rl3;
        split3(r0, rh0, rm0, rl0);
        split3(r1, rh1, rm1, rl1);
        split3(r2, rh2, rm2, rl2);
        split3(r3, rh3, rm3, rl3);
        // MFMA1: K0-7 = Ch.Rh, Cm.Rh ; K8-15 = Ch.Rm, Cm.Rm  (A = [Ch|Cm] both halves)
        __bf16 p0 = hh ? rm0 : rh0;
        __bf16 p1 = hh ? rm1 : rh1;
        __bf16 p2 = hh ? rm2 : rh2;
        __bf16 p3 = hh ? rm3 : rh3;
        bf16x8 b1;
        b1[0] = p0; b1[1] = p1; b1[2] = p2; b1[3] = p3;
        b1[4] = p0; b1[5] = p1; b1[6] = p2; b1[7] = p3;
        // MFMA2: K0-7 = Cl.Rh, Ch.Rl (A=[Cl|Ch]) ; K8-15 = Cm.Rl, cs*1 (A=[Cm|cs])
        __bf16 q0 = hh ? rl0 : rh0;
        __bf16 q1 = hh ? rl1 : rh1;
        __bf16 q2 = hh ? rl2 : rh2;
        __bf16 q3 = hh ? rl3 : rh3;
        bf16x8 b2;
        b2[0] = q0; b2[1] = q1; b2[2] = q2; b2[3] = q3;
        b2[4] = hh ? kone : rl0;
        b2[5] = hh ? kone : rl1;
        b2[6] = hh ? kone : rl2;
        b2[7] = hh ? kzb  : rl3;
        B1[rt] = b1; B2[rt] = b2;
    }
    __syncthreads();

    // ---- Pass 1: 32 col-tiles; per ct: 4 ds_read_b64 assemble a1/a2, 2
    //      chained MFMAs x RT (two concurrent rt-chains), per-QUAD min4 +
    //      (min, ct) tracker (strict < keeps FIRST ct).
    f32x16 kz = {0.0f,0.0f,0.0f,0.0f,0.0f,0.0f,0.0f,0.0f,
                 0.0f,0.0f,0.0f,0.0f,0.0f,0.0f,0.0f,0.0f};
    float runmin[RT][4];
    int   runct[RT][4];
#pragma unroll
    for (int rt = 0; rt < RT; ++rt)
#pragma unroll
        for (int gi = 0; gi < 4; ++gi) { runmin[rt][gi] = 3.0e38f; runct[rt][gi] = 0; }

    const size_t lnoff = (size_t)ln * 8;
    const char* bCh = (const char*)ldsH + 0 * (NP * 8) + lnoff;
    const char* bCm = (const char*)ldsH + 1 * (NP * 8) + lnoff;
    const char* bCl = (const char*)ldsH + 2 * (NP * 8) + lnoff;
    const char* bCs = (const char*)ldsH + 3 * (NP * 8) + lnoff;
    const char* bLo2 = hh ? bCm : bCl;   // a2 low  half source (hh-uniform ptr)
    const char* bHi2 = hh ? bCs : bCh;   // a2 high half source

    for (int ct = 0; ct < 32; ++ct) {
        const size_t off = (size_t)ct * 256;   // 32 cols x 8 B per half-plane
        bf16x8 a1, a2;
        *((uint2*)&a1)     = *(const uint2*)(bCh + off);
        *((uint2*)&a1 + 1) = *(const uint2*)(bCm + off);
        *((uint2*)&a2)     = *(const uint2*)(bLo2 + off);
        *((uint2*)&a2 + 1) = *(const uint2*)(bHi2 + off);
#pragma unroll
        for (int rt = 0; rt < RT; rt += 2) {
            f32x16 accA = __builtin_amdgcn_mfma_f32_32x32x16_bf16(a1, B1[rt],     kz, 0, 0, 0);
            f32x16 accB = __builtin_amdgcn_mfma_f32_32x32x16_bf16(a1, B1[rt + 1], kz, 0, 0, 0);
            accA = __builtin_amdgcn_mfma_f32_32x32x16_bf16(a2, B2[rt],     accA, 0, 0, 0);
            accB = __builtin_amdgcn_mfma_f32_32x32x16_bf16(a2, B2[rt + 1], accB, 0, 0, 0);
#pragma unroll
            for (int gi = 0; gi < 4; ++gi) {   // quad gi = abs cols ct*32+8*gi+4*hh+{0..3}
                float g = fminf(min3f(accA[4 * gi], accA[4 * gi + 1], accA[4 * gi + 2]),
                                accA[4 * gi + 3]);
                bool lt = g < runmin[rt][gi];      // strict < keeps FIRST ct
                runmin[rt][gi] = fminf(runmin[rt][gi], g);
                runct[rt][gi]  = lt ? ct : runct[rt][gi];
            }
#pragma unroll
            for (int gi = 0; gi < 4; ++gi) {
                float g = fminf(min3f(accB[4 * gi], accB[4 * gi + 1], accB[4 * gi + 2]),
                                accB[4 * gi + 3]);
                bool lt = g < runmin[rt + 1][gi];
                runmin[rt + 1][gi] = fminf(runmin[rt + 1][gi], g);
                runct[rt + 1][gi]  = lt ? ct : runct[rt + 1][gi];
            }
        }
    }

    // ---- Merge the 8 disjoint quad-candidates per row by lexicographic
    //      (val, abs base): contiguous disjoint ranges -> base order = column
    //      order -> reference first-index tie semantics. Then epilogue: lane
    //      handles its 2 assigned rows ((rt>>1)==hh): 4-col fp32 rescan from
    //      GLOBAL (bit-identical staging-chain recompute; ascending j +
    //      strict < = first-index argmin), winner xy, threshold.
    float sum = 0.0f;
#pragma unroll
    for (int rt = 0; rt < RT; ++rt) {
        float bv = runmin[rt][0];
        int   bc = runct[rt][0] * 32 + 4 * hh;
#pragma unroll
        for (int gi = 1; gi < 4; ++gi) {
            float v = runmin[rt][gi];
            int   c = runct[rt][gi] * 32 + 8 * gi + 4 * hh;
            bool take = (v < bv) || (v == bv && c < bc);
            bv = take ? v : bv;
            bc = take ? c : bc;
        }
        float ov = __shfl_xor(bv, 32);
        int   oc = __shfl_xor(bc, 32);
        bool take = (ov < bv) || (ov == bv && oc < bc);
        bv = take ? ov : bv;
        bc = take ? oc : bc;

        if ((rt >> 1) == hh) {               // hh=0 -> rt 0,1 ; hh=1 -> rt 2,3
            int n = wv * 128 + rt * 32 + ln;
            const float* pr = rowsrc + (size_t)n * FD;
            float t0 = fmaf(pr[5], s5, m5);
            float t1 = fmaf(pr[6], s6, m6);
            float t2 = fmaf(pr[7], s7, m7);
            float t3 = fmaf(pr[8], s8, m8);
            float vx = -0.5f * t0, vy = -0.5f * t1, vz = -0.5f * t2, vw = -0.5f * t3;
            float best = 3.0e38f;
            int   sel  = 0;
#pragma unroll
            for (int j = 0; j < 4; ++j) {
                const float* pc = colsrc + (size_t)(bc + j) * FD;
                float c0 = fmaf(pc[5], s5, m5);
                float c1 = fmaf(pc[6], s6, m6);
                float c2 = fmaf(pc[7], s7, m7);
                float c3 = fmaf(pc[8], s8, m8);
                float cs = 0.25f * (c0 * c0 + c1 * c1 + c2 * c2 + c3 * c3);
                float dd = fmaf(vx, c0, cs);
                dd = fmaf(vy, c1, dd);
                dd = fmaf(vz, c2, dd);
                dd = fmaf(vw, c3, dd);
                bool ltj = dd < best;        // ascending j + strict < = first idx
                best = fminf(best, dd);
                sel  = ltj ? j : sel;
            }
            int idx = bc + sel;
            const float* pw = colsrc + (size_t)idx * FD;
            float gx = fmaf(pw[0], std0, mean0);
            float gy = fmaf(pw[1], std1, mean1);
            float ax = fmaf(pr[0], std0, mean0);
            float ay = fmaf(pr[1], std1, mean1);
            float dx = ax - gx;
            float dy = ay - gy;
            float dist = sqrtf(dx * dx + dy * dy);
            if (best > rthr[rt]) dist = 1.0f;   // min_d > LATENT_DIST_THRESHOLD
            sum += dist;
        }
    }

    // ---- Reduce: wave shuffle, cross-wave LDS, one atomic per block.
    for (int o = 32; o > 0; o >>= 1) sum += __shfl_down(sum, o, 64);
    if ((tid & 63) == 0) red[tid >> 6] = sum;
    __syncthreads();
    if (tid == 0) {
        float s = red[0] + red[1] + red[2] + red[3]
                + red[4] + red[5] + red[6] + red[7];
        // out[b] = -(sum over 4 views x 2 dirs x 1024 rows) / 8192
        atomicAdd(&out[bid >> 3], s * (-1.0f / 8192.0f));
    }
}

extern "C" void kernel_launch(void* const* d_in, const int* in_sizes, int n_in,
                              void* d_out, int out_size, void* d_ws, size_t ws_size,
                              hipStream_t stream)
{
    const float* ag = (const float*)d_in[0];   // achieved_goal (128,4,1024,10)
    const float* dg = (const float*)d_in[1];   // desired_goal  (128,4,1024,10)
    const float* nm = (const float*)d_in[2];   // norm_mean (10,)
    const float* ns = (const float*)d_in[3];   // norm_std  (10,)

    hipMemsetAsync(d_out, 0, BSZ * sizeof(float), stream);   // out is accumulated
    chamfer_pairs<<<BSZ * 4 * 2, TPB, 0, stream>>>(ag, dg, nm, ns, (float*)d_out);
}